// Round 1
// baseline (18367.169 us; speedup 1.0000x reference)
//
#include <hip/hip_runtime.h>

#define NPART 131072
#define QDIM 32
#define DDIM 64
#define HDIM 50
#define STEPS 16
#define DT 0.1f
#define LN_EPS 1e-5f

__global__ __launch_bounds__(256, 1)
void ode2vae_fused(const float* __restrict__ z0,
                   const float* __restrict__ logp0,
                   const float* __restrict__ W1, const float* __restrict__ b1,
                   const float* __restrict__ g1, const float* __restrict__ be1,
                   const float* __restrict__ W2, const float* __restrict__ b2,
                   const float* __restrict__ g2, const float* __restrict__ be2,
                   const float* __restrict__ W3, const float* __restrict__ b3,
                   float* __restrict__ out)
{
    const int n = blockIdx.x * blockDim.x + threadIdx.x;
    if (n >= NPART) return;

    float z[DDIM];
    #pragma unroll
    for (int d = 0; d < DDIM; ++d) z[d] = z0[(size_t)n * DDIM + d];
    float lp = logp0[n];

    for (int s = 0; s < STEPS; ++s) {
        // ---------- layer 1: a1 = z @ W1 + b1 ----------
        float a1[HDIM];
        #pragma unroll
        for (int h = 0; h < HDIM; ++h) a1[h] = b1[h];
        #pragma unroll
        for (int d = 0; d < DDIM; ++d) {
            const float zd = z[d];
            #pragma unroll
            for (int h = 0; h < HDIM; ++h)
                a1[h] = fmaf(zd, W1[d * HDIM + h], a1[h]);
        }
        // LN1
        float m1 = 0.f;
        #pragma unroll
        for (int h = 0; h < HDIM; ++h) m1 += a1[h];
        m1 *= (1.f / HDIM);
        float v1 = 0.f;
        #pragma unroll
        for (int h = 0; h < HDIM; ++h) { const float t = a1[h] - m1; v1 = fmaf(t, t, v1); }
        v1 *= (1.f / HDIM);
        const float r1 = rsqrtf(v1 + LN_EPS);
        float xh1[HDIM], h1[HDIM];
        #pragma unroll
        for (int h = 0; h < HDIM; ++h) {
            xh1[h] = (a1[h] - m1) * r1;
            const float y = fmaf(xh1[h], g1[h], be1[h]);
            h1[h] = (y > 0.f) ? y : (__expf(y) - 1.f);   // celu, alpha=1
        }

        // ---------- layer 2: a2 = h1 @ W2 + b2 ----------
        float a2[HDIM];
        #pragma unroll
        for (int j = 0; j < HDIM; ++j) a2[j] = b2[j];
        #pragma unroll
        for (int h = 0; h < HDIM; ++h) {
            const float hh = h1[h];
            #pragma unroll
            for (int j = 0; j < HDIM; ++j)
                a2[j] = fmaf(hh, W2[h * HDIM + j], a2[j]);
        }
        // LN2
        float m2 = 0.f;
        #pragma unroll
        for (int j = 0; j < HDIM; ++j) m2 += a2[j];
        m2 *= (1.f / HDIM);
        float v2 = 0.f;
        #pragma unroll
        for (int j = 0; j < HDIM; ++j) { const float t = a2[j] - m2; v2 = fmaf(t, t, v2); }
        v2 *= (1.f / HDIM);
        const float r2 = rsqrtf(v2 + LN_EPS);
        float xh2[HDIM], h2[HDIM];
        #pragma unroll
        for (int j = 0; j < HDIM; ++j) {
            xh2[j] = (a2[j] - m2) * r2;
            const float y = fmaf(xh2[j], g2[j], be2[j]);
            h2[j] = (y > 0.f) ? y : (__expf(y) - 1.f);
        }

        // ---------- dv = h2 @ W3 + b3 (before trace so h2 can die) ----------
        float dv[QDIM];
        #pragma unroll
        for (int i = 0; i < QDIM; ++i) dv[i] = b3[i];
        #pragma unroll
        for (int j = 0; j < HDIM; ++j) {
            const float hj = h2[j];
            #pragma unroll
            for (int i = 0; i < QDIM; ++i)
                dv[i] = fmaf(hj, W3[j * QDIM + i], dv[i]);
        }

        // ---------- JVP weight vectors ----------
        // celu'(y) = 1 if y>0 else exp(y) = h+1  (h = celu(y) <= 0 there)
        float w1v[HDIM];
        #pragma unroll
        for (int h = 0; h < HDIM; ++h) {
            const float d1 = (h1[h] > 0.f) ? 1.f : (h1[h] + 1.f);
            w1v[h] = d1 * g1[h] * r1;
        }
        float w2v[HDIM];
        #pragma unroll
        for (int j = 0; j < HDIM; ++j) {
            const float d2 = (h2[j] > 0.f) ? 1.f : (h2[j] + 1.f);
            w2v[j] = d2 * g2[j] * r2;
        }

        // ---------- trace of Jacobian top-left QxQ block ----------
        float tr = 0.f;
        for (int i = 0; i < QDIM; ++i) {          // runtime loop: i indexes MEMORY only
            // tangent into layer1 is u = W1[i,:]
            float mu = 0.f, c = 0.f;
            #pragma unroll
            for (int h = 0; h < HDIM; ++h) {
                const float u = W1[i * HDIM + h];
                mu += u;
                c = fmaf(xh1[h], u, c);
            }
            mu *= (1.f / HDIM);
            c  *= (1.f / HDIM);

            float ta2[HDIM];
            #pragma unroll
            for (int j = 0; j < HDIM; ++j) ta2[j] = 0.f;
            #pragma unroll
            for (int h = 0; h < HDIM; ++h) {
                const float u   = W1[i * HDIM + h];
                const float th1 = w1v[h] * (u - mu - c * xh1[h]);
                #pragma unroll
                for (int j = 0; j < HDIM; ++j)
                    ta2[j] = fmaf(th1, W2[h * HDIM + j], ta2[j]);
            }

            float mt = 0.f, ct = 0.f;
            #pragma unroll
            for (int j = 0; j < HDIM; ++j) {
                mt += ta2[j];
                ct = fmaf(xh2[j], ta2[j], ct);
            }
            mt *= (1.f / HDIM);
            ct *= (1.f / HDIM);

            float acc = 0.f;
            #pragma unroll
            for (int j = 0; j < HDIM; ++j) {
                const float th2 = w2v[j] * (ta2[j] - mt - ct * xh2[j]);
                acc = fmaf(th2, W3[j * QDIM + i], acc);
            }
            tr += acc;
        }

        // ---------- Euler update ----------
        lp = fmaf(DT, -tr, lp);
        #pragma unroll
        for (int i = 0; i < QDIM; ++i) {
            z[QDIM + i] = fmaf(DT, z[i], z[QDIM + i]);   // uses OLD z[i]
            z[i]        = fmaf(DT, dv[i], z[i]);
        }

        // ---------- store trajectory ----------
        float* o = out + ((size_t)s * NPART + (size_t)n) * (DDIM + 1);
        #pragma unroll
        for (int d = 0; d < DDIM; ++d) o[d] = z[d];
        o[DDIM] = lp;
    }
}

extern "C" void kernel_launch(void* const* d_in, const int* in_sizes, int n_in,
                              void* d_out, int out_size, void* d_ws, size_t ws_size,
                              hipStream_t stream)
{
    const float* z0    = (const float*)d_in[0];
    const float* logp0 = (const float*)d_in[1];
    const float* W1    = (const float*)d_in[2];
    const float* b1    = (const float*)d_in[3];
    const float* g1    = (const float*)d_in[4];
    const float* be1   = (const float*)d_in[5];
    const float* W2    = (const float*)d_in[6];
    const float* b2    = (const float*)d_in[7];
    const float* g2    = (const float*)d_in[8];
    const float* be2   = (const float*)d_in[9];
    const float* W3    = (const float*)d_in[10];
    const float* b3    = (const float*)d_in[11];
    float* out = (float*)d_out;

    dim3 block(256);
    dim3 grid(NPART / 256);
    hipLaunchKernelGGL(ode2vae_fused, grid, block, 0, stream,
                       z0, logp0, W1, b1, g1, be1, W2, b2, g2, be2, W3, b3, out);
}

// Round 2
// 5832.490 us; speedup vs baseline: 3.1491x; 3.1491x over previous
//
#include <hip/hip_runtime.h>

#define NPART 131072
#define QDIM 32
#define DDIM 64
#define HDIM 50
#define STEPS 16
#define DT 0.1f
#define LN_EPS 1e-5f
#define INV_H 0.02f   // 1/50

// ---------------- setup: precompute U, V, s, w2rs into d_ws ----------------
// U[h][j] = sum_i W1[i*50+h] * W3[j*32+i]   (constant across particles/steps)
// V[h][j] = U[h][j] * W2[h*50+j]
// s[j]    = sum_h U[h][j]
// w2rs[h] = sum_j W2[h*50+j]
__global__ void ode2vae_setup(const float* __restrict__ W1,
                              const float* __restrict__ W2,
                              const float* __restrict__ W3,
                              float* __restrict__ ws)
{
    const int tid = threadIdx.x;
    for (int idx = tid; idx < HDIM * HDIM; idx += 256) {
        const int h = idx / HDIM, j = idx % HDIM;
        float u = 0.f;
        #pragma unroll
        for (int i = 0; i < QDIM; ++i)
            u = fmaf(W1[i * HDIM + h], W3[j * QDIM + i], u);
        ws[idx] = u;                              // U
        ws[HDIM * HDIM + idx] = u * W2[idx];      // V
    }
    if (tid < HDIM) {
        // s[j] computed straight from inputs (no dependence on U writes)
        float acc = 0.f;
        #pragma unroll
        for (int i = 0; i < QDIM; ++i) {
            float rs1 = 0.f;
            for (int h = 0; h < HDIM; ++h) rs1 += W1[i * HDIM + h];
            acc = fmaf(rs1, W3[tid * QDIM + i], acc);
        }
        ws[2 * HDIM * HDIM + tid] = acc;          // s
        float rs = 0.f;
        for (int j = 0; j < HDIM; ++j) rs += W2[tid * HDIM + j];
        ws[2 * HDIM * HDIM + HDIM + tid] = rs;    // w2rs
    }
}

// ---------------- main fused kernel ----------------
__global__ __launch_bounds__(64, 1)
void ode2vae_main(const float* __restrict__ z0, const float* __restrict__ logp0,
                  const float* __restrict__ W1, const float* __restrict__ b1,
                  const float* __restrict__ g1, const float* __restrict__ be1,
                  const float* __restrict__ W2, const float* __restrict__ b2,
                  const float* __restrict__ g2, const float* __restrict__ be2,
                  const float* __restrict__ W3, const float* __restrict__ b3,
                  const float* __restrict__ Umat, const float* __restrict__ Vmat,
                  const float* __restrict__ svec, const float* __restrict__ w2rs,
                  float* __restrict__ out)
{
    // per-lane LDS partitions, slot-major [slot][64] -> conflict-free
    __shared__ float lds[150 * 64];
    const int lane = threadIdx.x;
    const int n = blockIdx.x * 64 + lane;
    float* const Lxh  = lds + lane;            // slots 0..49: xh1, later x2
    float* const Lw1v = lds + 50 * 64 + lane;  // slots 50..99
    float* const Lw1x = lds + 100 * 64 + lane; // slots 100..149

    float z[DDIM];
    #pragma unroll
    for (int d = 0; d < DDIM; ++d) z[d] = z0[(size_t)n * DDIM + d];
    float lp = logp0[n];

    for (int s = 0; s < STEPS; ++s) {
        // ---- phase A: a1 = z @ W1 + b1 (h-space, regs) ----
        float a1[HDIM];
        #pragma unroll
        for (int h = 0; h < HDIM; ++h) a1[h] = b1[h];
        #pragma unroll
        for (int d = 0; d < DDIM; ++d) {
            const float zd = z[d];
            #pragma unroll
            for (int h = 0; h < HDIM; ++h)
                a1[h] = fmaf(zd, W1[d * HDIM + h], a1[h]);
        }
        // LN1 stats
        float m1 = 0.f;
        #pragma unroll
        for (int h = 0; h < HDIM; ++h) m1 += a1[h];
        m1 *= INV_H;
        float v1 = 0.f;
        #pragma unroll
        for (int h = 0; h < HDIM; ++h) { const float tt = a1[h] - m1; v1 = fmaf(tt, tt, v1); }
        const float r1 = rsqrtf(fmaf(v1, INV_H, LN_EPS));
        #pragma unroll
        for (int h = 0; h < HDIM; ++h) Lxh[h * 64] = (a1[h] - m1) * r1;

        // ---- sweep1 (runtime h): celu1, w1v/w1x -> LDS; a2,t accumulate ----
        float a2[HDIM], t[HDIM];
        #pragma unroll
        for (int j = 0; j < HDIM; ++j) { a2[j] = b2[j]; t[j] = 0.f; }
        #pragma unroll 2
        for (int h = 0; h < HDIM; ++h) {
            const float xh = Lxh[h * 64];
            const float gg = g1[h];
            const float y  = fmaf(xh, gg, be1[h]);
            const float e  = __expf(y);
            const float hh = (y > 0.f) ? y : (e - 1.f);     // celu
            const float d1 = (y > 0.f) ? 1.f : e;           // celu'
            const float w1vh = d1 * gg * r1;
            Lw1v[h * 64] = w1vh;
            Lw1x[h * 64] = w1vh * xh;
            const float* __restrict__ w2row = W2 + h * HDIM;
            const float* __restrict__ urow  = Umat + h * HDIM;
            #pragma unroll
            for (int j = 0; j < HDIM; ++j) {
                a2[j] = fmaf(hh, w2row[j], a2[j]);
                t[j]  = fmaf(xh, urow[j], t[j]);
            }
        }

        // ---- LN2 + w2v + scalars su,sy,tu,ty ----
        float m2 = 0.f;
        #pragma unroll
        for (int j = 0; j < HDIM; ++j) m2 += a2[j];
        m2 *= INV_H;
        float v2 = 0.f;
        #pragma unroll
        for (int j = 0; j < HDIM; ++j) { const float tt = a2[j] - m2; v2 = fmaf(tt, tt, v2); }
        const float r2 = rsqrtf(fmaf(v2, INV_H, LN_EPS));

        float x2[HDIM], w2v[HDIM];
        float su = 0.f, sy = 0.f, tu = 0.f, ty = 0.f;
        #pragma unroll
        for (int j = 0; j < HDIM; ++j) {
            const float xx = (a2[j] - m2) * r2;
            x2[j] = xx;
            Lxh[j * 64] = xx;                 // for dv pass (xh1 slots are dead)
            const float gg = g2[j];
            const float y  = fmaf(xx, gg, be2[j]);
            const float d2 = (y > 0.f) ? 1.f : __expf(y);
            const float wv = d2 * gg * r2;
            w2v[j] = wv;
            const float sw = svec[j] * wv;
            su += sw; sy = fmaf(sw, xx, sy);
            const float tw = t[j] * wv;
            tu += tw; ty = fmaf(tw, xx, ty);
        }
        // ---- q-pass: q1, q2 (over t), y3 ----
        float q1[HDIM], y3[HDIM];
        const float suH = su * INV_H, syH = sy * INV_H;
        const float tuH = tu * INV_H, tyH = ty * INV_H;
        #pragma unroll
        for (int j = 0; j < HDIM; ++j) {
            const float xx = x2[j], wv = w2v[j];
            q1[j] = svec[j] * wv - suH - syH * xx;
            t[j]  = t[j] * wv - tuH - tyH * xx;   // q2 in place
            y3[j] = xx * wv;
        }

        // ---- dv pass (runtime j, x2 from LDS) ----
        float dv[QDIM];
        #pragma unroll
        for (int i = 0; i < QDIM; ++i) dv[i] = b3[i];
        #pragma unroll 2
        for (int j = 0; j < HDIM; ++j) {
            const float xx = Lxh[j * 64];
            const float y  = fmaf(xx, g2[j], be2[j]);
            const float hh2 = (y > 0.f) ? y : (__expf(y) - 1.f);
            const float* __restrict__ w3row = W3 + j * QDIM;
            #pragma unroll
            for (int i = 0; i < QDIM; ++i)
                dv[i] = fmaf(hh2, w3row[i], dv[i]);
        }

        // ---- sweep2 (runtime h): six 50-dots -> trace terms ----
        float T1a = 0.f, T1b = 0.f, T1c = 0.f, S2 = 0.f, S3 = 0.f;
        #pragma unroll 2
        for (int h = 0; h < HDIM; ++h) {
            const float w1vh = Lw1v[h * 64];
            const float w1xh = Lw1x[h * 64];
            const float* __restrict__ w2row = W2 + h * HDIM;
            const float* __restrict__ urow  = Umat + h * HDIM;
            const float* __restrict__ vrow  = Vmat + h * HDIM;
            float dq1 = 0.f, dq2 = 0.f, ph = 0.f, duw = 0.f, duy = 0.f, dvw = 0.f;
            #pragma unroll
            for (int j = 0; j < HDIM; ++j) {
                const float w2_ = w2row[j];
                dq1 = fmaf(w2_, q1[j], dq1);
                dq2 = fmaf(w2_, t[j],  dq2);
                ph  = fmaf(w2_, x2[j], ph);
                const float u_ = urow[j];
                duw = fmaf(u_, w2v[j], duw);
                duy = fmaf(u_, y3[j],  duy);
                dvw = fmaf(vrow[j], w2v[j], dvw);
            }
            T1a = fmaf(w1vh, dvw, T1a);
            T1b = fmaf(w2rs[h] * w1vh, duw, T1b);
            T1c = fmaf(ph * w1vh, duy, T1c);
            S2  = fmaf(w1vh, dq1, S2);
            S3  = fmaf(w1xh, dq2, S3);
        }
        const float tr = T1a - (T1b + T1c + S2 + S3) * INV_H;

        // ---- Euler update + store ----
        lp = fmaf(-DT, tr, lp);
        #pragma unroll
        for (int i = 0; i < QDIM; ++i) {
            z[QDIM + i] = fmaf(DT, z[i], z[QDIM + i]);   // uses OLD z[i]
            z[i]        = fmaf(DT, dv[i], z[i]);
        }
        float* o = out + ((size_t)s * NPART + (size_t)n) * (DDIM + 1);
        #pragma unroll
        for (int d = 0; d < DDIM; ++d) o[d] = z[d];
        o[DDIM] = lp;
    }
}

extern "C" void kernel_launch(void* const* d_in, const int* in_sizes, int n_in,
                              void* d_out, int out_size, void* d_ws, size_t ws_size,
                              hipStream_t stream)
{
    const float* z0    = (const float*)d_in[0];
    const float* logp0 = (const float*)d_in[1];
    const float* W1    = (const float*)d_in[2];
    const float* b1    = (const float*)d_in[3];
    const float* g1    = (const float*)d_in[4];
    const float* be1   = (const float*)d_in[5];
    const float* W2    = (const float*)d_in[6];
    const float* b2    = (const float*)d_in[7];
    const float* g2    = (const float*)d_in[8];
    const float* be2   = (const float*)d_in[9];
    const float* W3    = (const float*)d_in[10];
    const float* b3    = (const float*)d_in[11];
    float* out = (float*)d_out;
    float* ws  = (float*)d_ws;

    hipLaunchKernelGGL(ode2vae_setup, dim3(1), dim3(256), 0, stream, W1, W2, W3, ws);

    const float* Umat = ws;
    const float* Vmat = ws + HDIM * HDIM;
    const float* svec = ws + 2 * HDIM * HDIM;
    const float* w2rsv = ws + 2 * HDIM * HDIM + HDIM;

    hipLaunchKernelGGL(ode2vae_main, dim3(NPART / 64), dim3(64), 0, stream,
                       z0, logp0, W1, b1, g1, be1, W2, b2, g2, be2, W3, b3,
                       Umat, Vmat, svec, w2rsv, out);
}

// Round 3
// 3916.875 us; speedup vs baseline: 4.6892x; 1.4891x over previous
//
#include <hip/hip_runtime.h>

#define NPART 131072
#define QDIM 32
#define DDIM 64
#define HDIM 50
#define STEPS 16
#define DT 0.1f
#define LN_EPS 1e-5f
#define INV_H 0.02f   // 1/50

typedef float f4a __attribute__((ext_vector_type(4)));              // aligned 16 (loads)
typedef float f4u __attribute__((ext_vector_type(4), aligned(4)));  // 4B-aligned stores

// ---------------- setup: W2T, UT, VT, svec, w2rs into d_ws ----------------
// UT[j][h] = sum_i W1[i*50+h] * W3[j*32+i]
// W2T[j][h] = W2[h*50+j];  VT = UT .* W2T
// svec[j] = sum_h UT[j][h];  w2rs[h] = sum_j W2[h*50+j]
__global__ void ode2vae_setup(const float* __restrict__ W1,
                              const float* __restrict__ W2,
                              const float* __restrict__ W3,
                              float* __restrict__ ws)
{
    const int tid = threadIdx.x;
    float* W2T = ws;
    float* UT  = ws + 2500;
    float* VT  = ws + 5000;
    float* sv  = ws + 7500;
    float* wrs = ws + 7550;
    for (int idx = tid; idx < HDIM * HDIM; idx += 256) {
        const int j = idx / HDIM, h = idx % HDIM;
        float u = 0.f;
        #pragma unroll
        for (int i = 0; i < QDIM; ++i)
            u = fmaf(W1[i * HDIM + h], W3[j * QDIM + i], u);
        const float w2 = W2[h * HDIM + j];
        W2T[idx] = w2;
        UT[idx]  = u;
        VT[idx]  = u * w2;
    }
    if (tid < HDIM) {
        float acc = 0.f;
        #pragma unroll
        for (int i = 0; i < QDIM; ++i) {
            float rs = 0.f;
            for (int h = 0; h < HDIM; ++h) rs += W1[i * HDIM + h];
            acc = fmaf(rs, W3[tid * QDIM + i], acc);
        }
        sv[tid] = acc;
        float rs2 = 0.f;
        for (int j = 0; j < HDIM; ++j) rs2 += W2[tid * HDIM + j];
        wrs[tid] = rs2;
    }
}

// 4-way partial 50-dot: r (uniform row) . v (h-register array)
#define DOT50(res, r, v)                                             \
    {                                                                \
        float p0 = 0.f, p1 = 0.f, p2 = 0.f, p3 = 0.f;                \
        _Pragma("unroll")                                            \
        for (int h = 0; h < 48; h += 4) {                            \
            p0 = fmaf((r)[h],     (v)[h],     p0);                   \
            p1 = fmaf((r)[h + 1], (v)[h + 1], p1);                   \
            p2 = fmaf((r)[h + 2], (v)[h + 2], p2);                   \
            p3 = fmaf((r)[h + 3], (v)[h + 3], p3);                   \
        }                                                            \
        p0 = fmaf((r)[48], (v)[48], p0);                             \
        p1 = fmaf((r)[49], (v)[49], p1);                             \
        res = (p0 + p1) + (p2 + p3);                                 \
    }

__global__ __launch_bounds__(64, 1)
void ode2vae_main(const float* __restrict__ z0, const float* __restrict__ logp0,
                  const float* __restrict__ W1, const float* __restrict__ b1,
                  const float* __restrict__ g1, const float* __restrict__ be1,
                  const float* __restrict__ W2, const float* __restrict__ b2,
                  const float* __restrict__ g2, const float* __restrict__ be2,
                  const float* __restrict__ W3, const float* __restrict__ b3,
                  const float* __restrict__ W2T, const float* __restrict__ UT,
                  const float* __restrict__ VT, const float* __restrict__ svec,
                  const float* __restrict__ w2rs,
                  float* __restrict__ out)
{
    // per-lane LDS, slot-major: slots 0..55 = z[0..55], 56..105 = x2, 106..155 = tw
    __shared__ float lds[156 * 64];
    const int lane = threadIdx.x;
    const int n = blockIdx.x * 64 + lane;
    float* const L = lds + lane;
#define LZ(d)  L[(d) * 64]
#define LX2(j) L[(56 + (j)) * 64]
#define LTW(j) L[(106 + (j)) * 64]

    // ---- prologue: load z (56 -> LDS, 8 -> regs) ----
    float zr[8];
    {
        const f4a* zp = (const f4a*)(z0 + (size_t)n * DDIM);
        #pragma unroll
        for (int k = 0; k < 14; ++k) {
            f4a v = zp[k];
            LZ(4 * k) = v[0]; LZ(4 * k + 1) = v[1];
            LZ(4 * k + 2) = v[2]; LZ(4 * k + 3) = v[3];
        }
        f4a v14 = zp[14];
        zr[0] = v14[0]; zr[1] = v14[1]; zr[2] = v14[2]; zr[3] = v14[3];
        f4a v15 = zp[15];
        zr[4] = v15[0]; zr[5] = v15[1]; zr[6] = v15[2]; zr[7] = v15[3];
    }
    float lp = logp0[n];

    for (int s = 0; s < STEPS; ++s) {
        // ======== phase A: ah = z @ W1 + b1 (rolled d, h in regs) ========
        float ah[HDIM];
        #pragma unroll
        for (int h = 0; h < HDIM; ++h) ah[h] = b1[h];
        {
            float zc = LZ(0);
            #pragma unroll 1
            for (int d = 0; d < 56; ++d) {
                const int dn = (d + 1 < 56) ? d + 1 : 0;
                const float zn = L[dn * 64];
                const float* __restrict__ r = W1 + d * HDIM;
                #pragma unroll
                for (int h = 0; h < HDIM; ++h) ah[h] = fmaf(zc, r[h], ah[h]);
                zc = zn;
            }
        }
        #pragma unroll
        for (int dd = 0; dd < 8; ++dd) {
            const float* __restrict__ r = W1 + (56 + dd) * HDIM;
            #pragma unroll
            for (int h = 0; h < HDIM; ++h) ah[h] = fmaf(zr[dd], r[h], ah[h]);
        }

        // ======== LN1 + hh (celu) + w1v; ah becomes xh1 ========
        float m1, r1;
        {
            float p0 = 0.f, p1 = 0.f, p2 = 0.f, p3 = 0.f;
            #pragma unroll
            for (int h = 0; h < 48; h += 4) { p0 += ah[h]; p1 += ah[h+1]; p2 += ah[h+2]; p3 += ah[h+3]; }
            m1 = ((p0 + ah[48]) + (p1 + ah[49]) + (p2 + p3)) * INV_H;
            float q0 = 0.f, q1_ = 0.f, q2_ = 0.f, q3 = 0.f;
            #pragma unroll
            for (int h = 0; h < 48; h += 4) {
                float t0 = ah[h] - m1, t1 = ah[h+1] - m1, t2 = ah[h+2] - m1, t3 = ah[h+3] - m1;
                q0 = fmaf(t0, t0, q0); q1_ = fmaf(t1, t1, q1_);
                q2_ = fmaf(t2, t2, q2_); q3 = fmaf(t3, t3, q3);
            }
            float t0 = ah[48] - m1, t1 = ah[49] - m1;
            q0 = fmaf(t0, t0, q0); q1_ = fmaf(t1, t1, q1_);
            r1 = rsqrtf(fmaf((q0 + q1_) + (q2_ + q3), INV_H, LN_EPS));
        }
        float hh[HDIM], w1v[HDIM];
        #pragma unroll
        for (int h = 0; h < HDIM; ++h) {
            const float xh = (ah[h] - m1) * r1;
            ah[h] = xh;                                   // xh1
            const float gg = g1[h];
            const float y = fmaf(xh, gg, be1[h]);
            const float e = __expf(y);
            hh[h]  = (y > 0.f) ? y : (e - 1.f);           // celu
            w1v[h] = ((y > 0.f) ? 1.f : e) * (gg * r1);
        }

        // ======== a2 = hh @ W2 + b2 (rolled j), raw a2 -> LDS ========
        float m2a = 0.f, v2a = 0.f;
        #pragma unroll 1
        for (int j = 0; j < HDIM; ++j) {
            const float* __restrict__ r = W2T + j * HDIM;
            float a2j;
            DOT50(a2j, r, hh);
            a2j += b2[j];
            LX2(j) = a2j;
            m2a += a2j;
            v2a = fmaf(a2j, a2j, v2a);
        }
        const float m2 = m2a * INV_H;
        float var2 = v2a * INV_H - m2 * m2;
        var2 = var2 > 0.f ? var2 : 0.f;
        const float r2 = rsqrtf(var2 + LN_EPS);

        // ======== scalars loop: t, w2v, tw; convert x2 in LDS ========
        float suA = 0.f, syA = 0.f, tuA = 0.f, tyA = 0.f;
        #pragma unroll 1
        for (int j = 0; j < HDIM; ++j) {
            const float a2r = LX2(j);
            const float x2 = (a2r - m2) * r2;
            LX2(j) = x2;
            const float* __restrict__ r = UT + j * HDIM;
            float t;
            DOT50(t, r, ah);                              // xh1
            const float g2j = g2[j], be2j = be2[j];
            const float y = fmaf(x2, g2j, be2j);
            const float e = __expf(y);
            const float w2vj = ((y > 0.f) ? 1.f : e) * (g2j * r2);
            const float tw = w2vj * t;
            LTW(j) = tw;
            tuA += tw; tyA = fmaf(tw, x2, tyA);
            const float sw = svec[j] * w2vj;
            suA += sw; syA = fmaf(sw, x2, syA);
        }
        const float suH = suA * INV_H, syH = syA * INV_H;
        const float tuH = tuA * INV_H, tyH = tyA * INV_H;

        // ======== w1x: ah = w1v * xh1 (in place) ========
        #pragma unroll
        for (int h = 0; h < HDIM; ++h) ah[h] *= w1v[h];

        // ======== F1 (W2T rows): S2, S3, ph[] ========
        float S2 = 0.f, S3 = 0.f;
        float ph[HDIM];
        #pragma unroll
        for (int h = 0; h < HDIM; ++h) ph[h] = 0.f;
        #pragma unroll 1
        for (int j = 0; j < HDIM; ++j) {
            const float* __restrict__ r = W2T + j * HDIM;
            const float x2 = LX2(j);
            const float tw = LTW(j);
            const float g2j = g2[j], be2j = be2[j];
            const float y = fmaf(x2, g2j, be2j);
            const float e = __expf(y);
            const float w2vj = ((y > 0.f) ? 1.f : e) * (g2j * r2);
            const float q1 = fmaf(-syH, x2, svec[j] * w2vj - suH);
            const float q2 = fmaf(-tyH, x2, tw - tuH);
            float c10 = 0.f, c11 = 0.f, c12 = 0.f, c13 = 0.f;
            float c30 = 0.f, c31 = 0.f, c32 = 0.f, c33 = 0.f;
            #pragma unroll
            for (int h = 0; h < 48; h += 4) {
                c10 = fmaf(r[h],   w1v[h],   c10); c30 = fmaf(r[h],   ah[h],   c30);
                c11 = fmaf(r[h+1], w1v[h+1], c11); c31 = fmaf(r[h+1], ah[h+1], c31);
                c12 = fmaf(r[h+2], w1v[h+2], c12); c32 = fmaf(r[h+2], ah[h+2], c32);
                c13 = fmaf(r[h+3], w1v[h+3], c13); c33 = fmaf(r[h+3], ah[h+3], c33);
                ph[h]   = fmaf(r[h],   x2, ph[h]);
                ph[h+1] = fmaf(r[h+1], x2, ph[h+1]);
                ph[h+2] = fmaf(r[h+2], x2, ph[h+2]);
                ph[h+3] = fmaf(r[h+3], x2, ph[h+3]);
            }
            c10 = fmaf(r[48], w1v[48], c10); c30 = fmaf(r[48], ah[48], c30);
            c11 = fmaf(r[49], w1v[49], c11); c31 = fmaf(r[49], ah[49], c31);
            ph[48] = fmaf(r[48], x2, ph[48]);
            ph[49] = fmaf(r[49], x2, ph[49]);
            S2 = fmaf(q1, (c10 + c11) + (c12 + c13), S2);
            S3 = fmaf(q2, (c30 + c31) + (c32 + c33), S3);
        }

        // ======== w1b: ah = w1v * w2rs (in place, w1x dead) ========
        #pragma unroll
        for (int h = 0; h < HDIM; ++h) ah[h] = w1v[h] * w2rs[h];

        // ======== F2 (UT rows): T1b, duy[] ========
        float T1b = 0.f;
        float duy[HDIM];
        #pragma unroll
        for (int h = 0; h < HDIM; ++h) duy[h] = 0.f;
        #pragma unroll 1
        for (int j = 0; j < HDIM; ++j) {
            const float* __restrict__ r = UT + j * HDIM;
            const float x2 = LX2(j);
            const float g2j = g2[j], be2j = be2[j];
            const float y = fmaf(x2, g2j, be2j);
            const float e = __expf(y);
            const float w2vj = ((y > 0.f) ? 1.f : e) * (g2j * r2);
            const float y3 = x2 * w2vj;
            float c0 = 0.f, c1 = 0.f, c2 = 0.f, c3 = 0.f;
            #pragma unroll
            for (int h = 0; h < 48; h += 4) {
                c0 = fmaf(r[h],   ah[h],   c0);
                c1 = fmaf(r[h+1], ah[h+1], c1);
                c2 = fmaf(r[h+2], ah[h+2], c2);
                c3 = fmaf(r[h+3], ah[h+3], c3);
                duy[h]   = fmaf(r[h],   y3, duy[h]);
                duy[h+1] = fmaf(r[h+1], y3, duy[h+1]);
                duy[h+2] = fmaf(r[h+2], y3, duy[h+2]);
                duy[h+3] = fmaf(r[h+3], y3, duy[h+3]);
            }
            c0 = fmaf(r[48], ah[48], c0);
            c1 = fmaf(r[49], ah[49], c1);
            duy[48] = fmaf(r[48], y3, duy[48]);
            duy[49] = fmaf(r[49], y3, duy[49]);
            T1b = fmaf(w2vj, (c0 + c1) + (c2 + c3), T1b);
        }

        // ======== T1c = sum_h w1v*ph*duy ========
        float T1c;
        {
            float p0 = 0.f, p1 = 0.f, p2 = 0.f, p3 = 0.f;
            #pragma unroll
            for (int h = 0; h < 48; h += 4) {
                p0 = fmaf(w1v[h]   * ph[h],   duy[h],   p0);
                p1 = fmaf(w1v[h+1] * ph[h+1], duy[h+1], p1);
                p2 = fmaf(w1v[h+2] * ph[h+2], duy[h+2], p2);
                p3 = fmaf(w1v[h+3] * ph[h+3], duy[h+3], p3);
            }
            p0 = fmaf(w1v[48] * ph[48], duy[48], p0);
            p1 = fmaf(w1v[49] * ph[49], duy[49], p1);
            T1c = (p0 + p1) + (p2 + p3);
        }

        // ======== F3 (VT rows): T1a ========
        float T1a = 0.f;
        #pragma unroll 1
        for (int j = 0; j < HDIM; ++j) {
            const float* __restrict__ r = VT + j * HDIM;
            const float x2 = LX2(j);
            const float g2j = g2[j], be2j = be2[j];
            const float y = fmaf(x2, g2j, be2j);
            const float e = __expf(y);
            const float w2vj = ((y > 0.f) ? 1.f : e) * (g2j * r2);
            float cv;
            DOT50(cv, r, w1v);
            T1a = fmaf(w2vj, cv, T1a);
        }
        const float tr = T1a - (T1b + T1c + S2 + S3) * INV_H;

        // ======== dv = h2 @ W3 + b3 (rolled j) ========
        float dv[QDIM];
        #pragma unroll
        for (int i = 0; i < QDIM; ++i) dv[i] = b3[i];
        #pragma unroll 1
        for (int j = 0; j < HDIM; ++j) {
            const float x2 = LX2(j);
            const float y = fmaf(x2, g2[j], be2[j]);
            const float e = __expf(y);
            const float h2 = (y > 0.f) ? y : (e - 1.f);
            const float* __restrict__ r = W3 + j * QDIM;
            #pragma unroll
            for (int i = 0; i < QDIM; ++i) dv[i] = fmaf(h2, r[i], dv[i]);
        }

        // ======== Euler update + store ========
        lp = fmaf(-DT, tr, lp);
        float zq[QDIM], zs[QDIM];
        #pragma unroll
        for (int i = 0; i < QDIM; ++i) zq[i] = LZ(i);
        #pragma unroll
        for (int i = 0; i < 24; ++i) zs[i] = LZ(32 + i);
        #pragma unroll
        for (int i = 24; i < QDIM; ++i) zs[i] = zr[i - 24];
        #pragma unroll
        for (int i = 0; i < QDIM; ++i) {
            zs[i] = fmaf(DT, zq[i], zs[i]);      // uses OLD zq
            zq[i] = fmaf(DT, dv[i], zq[i]);
        }
        #pragma unroll
        for (int i = 0; i < QDIM; ++i) LZ(i) = zq[i];
        #pragma unroll
        for (int i = 0; i < 24; ++i) LZ(32 + i) = zs[i];
        #pragma unroll
        for (int i = 24; i < QDIM; ++i) zr[i - 24] = zs[i];

        float* o = out + ((size_t)s * NPART + (size_t)n) * (DDIM + 1);
        #pragma unroll
        for (int k = 0; k < 8; ++k) {
            f4u v = {zq[4*k], zq[4*k+1], zq[4*k+2], zq[4*k+3]};
            *(f4u*)(o + 4 * k) = v;
        }
        #pragma unroll
        for (int k = 0; k < 8; ++k) {
            f4u v = {zs[4*k], zs[4*k+1], zs[4*k+2], zs[4*k+3]};
            *(f4u*)(o + 32 + 4 * k) = v;
        }
        o[DDIM] = lp;
    }
}

extern "C" void kernel_launch(void* const* d_in, const int* in_sizes, int n_in,
                              void* d_out, int out_size, void* d_ws, size_t ws_size,
                              hipStream_t stream)
{
    const float* z0    = (const float*)d_in[0];
    const float* logp0 = (const float*)d_in[1];
    const float* W1    = (const float*)d_in[2];
    const float* b1    = (const float*)d_in[3];
    const float* g1    = (const float*)d_in[4];
    const float* be1   = (const float*)d_in[5];
    const float* W2    = (const float*)d_in[6];
    const float* b2    = (const float*)d_in[7];
    const float* g2    = (const float*)d_in[8];
    const float* be2   = (const float*)d_in[9];
    const float* W3    = (const float*)d_in[10];
    const float* b3    = (const float*)d_in[11];
    float* out = (float*)d_out;
    float* ws  = (float*)d_ws;

    hipLaunchKernelGGL(ode2vae_setup, dim3(1), dim3(256), 0, stream, W1, W2, W3, ws);

    const float* W2T  = ws;
    const float* UT   = ws + 2500;
    const float* VT   = ws + 5000;
    const float* svec = ws + 7500;
    const float* w2rsv = ws + 7550;

    hipLaunchKernelGGL(ode2vae_main, dim3(NPART / 64), dim3(64), 0, stream,
                       z0, logp0, W1, b1, g1, be1, W2, b2, g2, be2, W3, b3,
                       W2T, UT, VT, svec, w2rsv, out);
}

// Round 4
// 3211.513 us; speedup vs baseline: 5.7192x; 1.2196x over previous
//
#include <hip/hip_runtime.h>
#include <hip/hip_fp16.h>

#define NPART 131072
#define QDIM 32
#define DDIM 64
#define HDIM 50
#define STEPS 16
#define DT 0.1f
#define LN_EPS 1e-5f
#define INV_H 0.02f   // 1/50

typedef float f4a __attribute__((ext_vector_type(4)));              // aligned 16 (loads)
typedef float f4u __attribute__((ext_vector_type(4), aligned(4)));  // 4B-aligned stores

// ---- f16 pair pack/unpack (x2 in low half, tw in high half) ----
__device__ __forceinline__ float pack2h(float x, float t) {
    const unsigned hx = __half_as_ushort(__float2half_rn(x));
    const unsigned ht = __half_as_ushort(__float2half_rn(t));
    return __uint_as_float((ht << 16) | hx);
}
__device__ __forceinline__ void unpack_lo(float f, float& x) {
    const unsigned u = __float_as_uint(f);
    x = __half2float(__ushort_as_half((unsigned short)(u & 0xffff)));
}
__device__ __forceinline__ void unpack2h(float f, float& x, float& t) {
    const unsigned u = __float_as_uint(f);
    x = __half2float(__ushort_as_half((unsigned short)(u & 0xffff)));
    t = __half2float(__ushort_as_half((unsigned short)(u >> 16)));
}

// ---------------- setup: W1T, W2T, UT, M, svec into d_ws ----------------
// W1T[h][d] = W1[d][h]                        (50x64)
// W2T[j][h] = W2[h][j]                        (50x50)
// UT [j][h] = sum_i W1[i*50+h] * W3[j*32+i]   (50x50)
// M  [j][h] = UT[j][h] * (W2T[j][h] - INV_H * w2rs[h]),  w2rs[h] = sum_j W2[h][j]
// svec[j]   = sum_h UT[j][h]
__global__ void ode2vae_setup(const float* __restrict__ W1,
                              const float* __restrict__ W2,
                              const float* __restrict__ W3,
                              float* __restrict__ ws)
{
    const int tid = threadIdx.x;
    float* W1T = ws;
    float* W2T = ws + 3200;
    float* UT  = ws + 5700;
    float* M   = ws + 8200;
    float* sv  = ws + 10700;
    for (int idx = tid; idx < HDIM * DDIM; idx += 256) {
        const int h = idx / DDIM, d = idx % DDIM;
        W1T[idx] = W1[d * HDIM + h];
    }
    for (int idx = tid; idx < HDIM * HDIM; idx += 256) {
        const int j = idx / HDIM, h = idx % HDIM;
        float u = 0.f;
        #pragma unroll
        for (int i = 0; i < QDIM; ++i)
            u = fmaf(W1[i * HDIM + h], W3[j * QDIM + i], u);
        const float w2 = W2[h * HDIM + j];
        float rs = 0.f;
        for (int jj = 0; jj < HDIM; ++jj) rs += W2[h * HDIM + jj];
        W2T[idx] = w2;
        UT[idx]  = u;
        M[idx]   = u * (w2 - INV_H * rs);
    }
    if (tid < HDIM) {
        float acc = 0.f;
        #pragma unroll
        for (int i = 0; i < QDIM; ++i) {
            float rs1 = 0.f;
            for (int h = 0; h < HDIM; ++h) rs1 += W1[i * HDIM + h];
            acc = fmaf(rs1, W3[tid * QDIM + i], acc);
        }
        sv[tid] = acc;
    }
}

// 4-way partial 50-dot: r (uniform row) . v (register array)
#define DOT50(res, r, v)                                             \
    {                                                                \
        float p0 = 0.f, p1 = 0.f, p2 = 0.f, p3 = 0.f;                \
        _Pragma("unroll")                                            \
        for (int h_ = 0; h_ < 48; h_ += 4) {                         \
            p0 = fmaf((r)[h_],     (v)[h_],     p0);                 \
            p1 = fmaf((r)[h_ + 1], (v)[h_ + 1], p1);                 \
            p2 = fmaf((r)[h_ + 2], (v)[h_ + 2], p2);                 \
            p3 = fmaf((r)[h_ + 3], (v)[h_ + 3], p3);                 \
        }                                                            \
        p0 = fmaf((r)[48], (v)[48], p0);                             \
        p1 = fmaf((r)[49], (v)[49], p1);                             \
        res = (p0 + p1) + (p2 + p3);                                 \
    }

__global__ __launch_bounds__(64, 2)
void ode2vae_main(const float* __restrict__ z0, const float* __restrict__ logp0,
                  const float* __restrict__ b1, const float* __restrict__ g1,
                  const float* __restrict__ be1,
                  const float* __restrict__ b2, const float* __restrict__ g2,
                  const float* __restrict__ be2,
                  const float* __restrict__ W3, const float* __restrict__ b3,
                  const float* __restrict__ W1T, const float* __restrict__ W2T,
                  const float* __restrict__ UT, const float* __restrict__ M,
                  const float* __restrict__ svec,
                  float* __restrict__ out)
{
    // ONE 50-slot per-lane LDS array, slot-major [slot][64]:
    // holds a1 raw -> a2 raw -> packed f16(x2, tw)
    __shared__ float lds[HDIM * 64];
    const int lane = threadIdx.x;
    const int n = blockIdx.x * 64 + lane;
    float* const L = lds + lane;
#define SLOT(k) L[(k) * 64]

    float z[DDIM];
    {
        const f4a* zp = (const f4a*)(z0 + (size_t)n * DDIM);
        #pragma unroll
        for (int k = 0; k < 16; ++k) {
            f4a v = zp[k];
            z[4 * k]     = v[0]; z[4 * k + 1] = v[1];
            z[4 * k + 2] = v[2]; z[4 * k + 3] = v[3];
        }
    }
    float lp = logp0[n];

    for (int s = 0; s < STEPS; ++s) {
        // ======== phase A (rolled h): a1[h] = z . W1T_row_h + b1[h] -> LDS ========
        float m1a = 0.f, v1a = 0.f;
        #pragma unroll 1
        for (int h = 0; h < HDIM; ++h) {
            const float* __restrict__ r = W1T + h * DDIM;
            float p0 = 0.f, p1 = 0.f, p2 = 0.f, p3 = 0.f;
            #pragma unroll
            for (int d = 0; d < DDIM; d += 4) {
                p0 = fmaf(r[d],     z[d],     p0);
                p1 = fmaf(r[d + 1], z[d + 1], p1);
                p2 = fmaf(r[d + 2], z[d + 2], p2);
                p3 = fmaf(r[d + 3], z[d + 3], p3);
            }
            const float a1h = ((p0 + p1) + (p2 + p3)) + b1[h];
            SLOT(h) = a1h;
            m1a += a1h;
            v1a = fmaf(a1h, a1h, v1a);
        }
        const float m1 = m1a * INV_H;
        float var1 = v1a * INV_H - m1 * m1;
        var1 = var1 > 0.f ? var1 : 0.f;
        const float r1 = rsqrtf(var1 + LN_EPS);

        // ======== extract (unrolled h): xh1, hh, w1v ========
        float xh1[HDIM], hh[HDIM], w1v[HDIM];
        #pragma unroll
        for (int h = 0; h < HDIM; ++h) {
            const float xh = (SLOT(h) - m1) * r1;
            xh1[h] = xh;
            const float gg = g1[h];
            const float y = fmaf(xh, gg, be1[h]);
            const float e = __expf(y);
            hh[h]  = (y > 0.f) ? y : (e - 1.f);           // celu
            w1v[h] = ((y > 0.f) ? 1.f : e) * (gg * r1);
        }

        // ======== a2 loop (rolled j): raw a2 -> same LDS slots ========
        float m2a = 0.f, v2a = 0.f;
        #pragma unroll 1
        for (int j = 0; j < HDIM; ++j) {
            const float* __restrict__ r = W2T + j * HDIM;
            float a2j;
            DOT50(a2j, r, hh);
            a2j += b2[j];
            SLOT(j) = a2j;
            m2a += a2j;
            v2a = fmaf(a2j, a2j, v2a);
        }
        const float m2 = m2a * INV_H;
        float var2 = v2a * INV_H - m2 * m2;
        var2 = var2 > 0.f ? var2 : 0.f;
        const float r2 = rsqrtf(var2 + LN_EPS);

        // ======== scalars loop (rolled j): x2, t, tw; pack f16 in place ========
        float suA = 0.f, syA = 0.f, tuA = 0.f, tyA = 0.f;
        #pragma unroll 1
        for (int j = 0; j < HDIM; ++j) {
            const float x2 = (SLOT(j) - m2) * r2;
            const float* __restrict__ r = UT + j * HDIM;
            float t;
            DOT50(t, r, xh1);
            const float g2j = g2[j];
            const float y = fmaf(x2, g2j, be2[j]);
            const float e = __expf(y);
            const float w2vj = ((y > 0.f) ? 1.f : e) * (g2j * r2);
            const float tw = w2vj * t;
            SLOT(j) = pack2h(x2, tw);
            tuA += tw; tyA = fmaf(tw, x2, tyA);
            const float sw = svec[j] * w2vj;
            suA += sw; syA = fmaf(sw, x2, syA);
        }
        const float suH = suA * INV_H, syH = syA * INV_H;
        const float tuH = tuA * INV_H, tyH = tyA * INV_H;

        // ======== w1x: xh1 *= w1v (in place; xh1 dead) ========
        #pragma unroll
        for (int h = 0; h < HDIM; ++h) xh1[h] *= w1v[h];

        // ======== F2 (UT rows): duy[h] += UT[j][h] * y3_j ========
        float duy[HDIM];
        #pragma unroll
        for (int h = 0; h < HDIM; ++h) duy[h] = 0.f;
        #pragma unroll 1
        for (int j = 0; j < HDIM; ++j) {
            const float* __restrict__ r = UT + j * HDIM;
            float x2; unpack_lo(SLOT(j), x2);
            const float g2j = g2[j];
            const float y = fmaf(x2, g2j, be2[j]);
            const float e = __expf(y);
            const float w2vj = ((y > 0.f) ? 1.f : e) * (g2j * r2);
            const float y3 = x2 * w2vj;
            #pragma unroll
            for (int h = 0; h < HDIM; ++h)
                duy[h] = fmaf(r[h], y3, duy[h]);
        }
        // wduy = w1v * duy (in place)
        #pragma unroll
        for (int h = 0; h < HDIM; ++h) duy[h] *= w1v[h];

        // ======== F1 (W2T rows): S2, S3, T1c ========
        float S2 = 0.f, S3 = 0.f, T1c = 0.f;
        #pragma unroll 1
        for (int j = 0; j < HDIM; ++j) {
            const float* __restrict__ r = W2T + j * HDIM;
            float x2, tw; unpack2h(SLOT(j), x2, tw);
            const float g2j = g2[j];
            const float y = fmaf(x2, g2j, be2[j]);
            const float e = __expf(y);
            const float w2vj = ((y > 0.f) ? 1.f : e) * (g2j * r2);
            const float q1 = fmaf(-syH, x2, svec[j] * w2vj - suH);
            const float q2 = fmaf(-tyH, x2, tw - tuH);
            float c10 = 0.f, c11 = 0.f, c30 = 0.f, c31 = 0.f, cT0 = 0.f, cT1 = 0.f;
            #pragma unroll
            for (int h = 0; h < HDIM; h += 2) {
                c10 = fmaf(r[h],   w1v[h],   c10);
                c11 = fmaf(r[h+1], w1v[h+1], c11);
                c30 = fmaf(r[h],   xh1[h],   c30);   // w1x
                c31 = fmaf(r[h+1], xh1[h+1], c31);
                cT0 = fmaf(r[h],   duy[h],   cT0);   // wduy
                cT1 = fmaf(r[h+1], duy[h+1], cT1);
            }
            S2  = fmaf(q1, c10 + c11, S2);
            S3  = fmaf(q2, c30 + c31, S3);
            T1c = fmaf(x2, cT0 + cT1, T1c);
        }

        // ======== F3 (M rows): T1A = T1a - T1b/H ========
        float T1A = 0.f;
        #pragma unroll 1
        for (int j = 0; j < HDIM; ++j) {
            const float* __restrict__ r = M + j * HDIM;
            float x2; unpack_lo(SLOT(j), x2);
            const float g2j = g2[j];
            const float y = fmaf(x2, g2j, be2[j]);
            const float e = __expf(y);
            const float w2vj = ((y > 0.f) ? 1.f : e) * (g2j * r2);
            float cv;
            DOT50(cv, r, w1v);
            T1A = fmaf(w2vj, cv, T1A);
        }
        const float tr = T1A - (T1c + S2 + S3) * INV_H;

        // ======== dv = h2 @ W3 + b3 (rolled j) ========
        float dv[QDIM];
        #pragma unroll
        for (int i = 0; i < QDIM; ++i) dv[i] = b3[i];
        #pragma unroll 1
        for (int j = 0; j < HDIM; ++j) {
            float x2; unpack_lo(SLOT(j), x2);
            const float y = fmaf(x2, g2[j], be2[j]);
            const float e = __expf(y);
            const float h2 = (y > 0.f) ? y : (e - 1.f);
            const float* __restrict__ r = W3 + j * QDIM;
            #pragma unroll
            for (int i = 0; i < QDIM; ++i) dv[i] = fmaf(h2, r[i], dv[i]);
        }

        // ======== Euler update + store ========
        lp = fmaf(-DT, tr, lp);
        #pragma unroll
        for (int i = 0; i < QDIM; ++i) {
            z[QDIM + i] = fmaf(DT, z[i], z[QDIM + i]);   // uses OLD z[i]
            z[i]        = fmaf(DT, dv[i], z[i]);
        }
        float* o = out + ((size_t)s * NPART + (size_t)n) * (DDIM + 1);
        #pragma unroll
        for (int k = 0; k < 16; ++k) {
            f4u v = {z[4*k], z[4*k+1], z[4*k+2], z[4*k+3]};
            *(f4u*)(o + 4 * k) = v;
        }
        o[DDIM] = lp;
    }
}

extern "C" void kernel_launch(void* const* d_in, const int* in_sizes, int n_in,
                              void* d_out, int out_size, void* d_ws, size_t ws_size,
                              hipStream_t stream)
{
    const float* z0    = (const float*)d_in[0];
    const float* logp0 = (const float*)d_in[1];
    const float* W1    = (const float*)d_in[2];
    const float* b1    = (const float*)d_in[3];
    const float* g1    = (const float*)d_in[4];
    const float* be1   = (const float*)d_in[5];
    const float* W2    = (const float*)d_in[6];
    const float* b2    = (const float*)d_in[7];
    const float* g2    = (const float*)d_in[8];
    const float* be2   = (const float*)d_in[9];
    const float* W3    = (const float*)d_in[10];
    const float* b3    = (const float*)d_in[11];
    float* out = (float*)d_out;
    float* ws  = (float*)d_ws;

    hipLaunchKernelGGL(ode2vae_setup, dim3(1), dim3(256), 0, stream, W1, W2, W3, ws);

    const float* W1T  = ws;
    const float* W2T  = ws + 3200;
    const float* UT   = ws + 5700;
    const float* Mm   = ws + 8200;
    const float* svec = ws + 10700;

    hipLaunchKernelGGL(ode2vae_main, dim3(NPART / 64), dim3(64), 0, stream,
                       z0, logp0, b1, g1, be1, b2, g2, be2, W3, b3,
                       W1T, W2T, UT, Mm, svec, out);
}